// Round 2
// 677.842 us; speedup vs baseline: 1.1266x; 1.1266x over previous
//
#include <hip/hip_runtime.h>
#include <hip/hip_bf16.h>
#include <cstdint>
#include <cstddef>

#define EPS_BN 1e-5f
#define LDK 40          // LDS leading-dim stride in ushorts
#define TILE (128 * LDK)

typedef __attribute__((ext_vector_type(8))) __bf16 bf16x8;
typedef __attribute__((ext_vector_type(4))) float f32x4;

__device__ __forceinline__ unsigned short f2b(float f) {
    __hip_bfloat16 h = __float2bfloat16(f);
    return __builtin_bit_cast(unsigned short, h);
}
__device__ __forceinline__ unsigned int pack2(float a, float b) {
    return (unsigned int)f2b(a) | ((unsigned int)f2b(b) << 16);
}
// wait lgkmcnt(0) only (vmcnt=63, expcnt=7 untouched), then raw barrier
__device__ __forceinline__ void lgkm_barrier() {
    __builtin_amdgcn_s_waitcnt(0xC07F);
    __builtin_amdgcn_s_barrier();
}

// ---------------- prep kernels ----------------

__global__ void prep_bn_kernel(const float* __restrict__ g1, const float* __restrict__ b1,
                               const float* __restrict__ m1, const float* __restrict__ v1,
                               const float* __restrict__ g2, const float* __restrict__ b2,
                               const float* __restrict__ m2, const float* __restrict__ v2,
                               const float* __restrict__ g3, const float* __restrict__ b3,
                               const float* __restrict__ m3, const float* __restrict__ v3,
                               float* __restrict__ bias1, float* __restrict__ bias2,
                               float* __restrict__ bias3) {
    int t = blockIdx.x * 256 + threadIdx.x;
    if (t < 256) {
        float inv = g1[t] * rsqrtf(v1[t] + EPS_BN);
        bias1[t] = b1[t] - m1[t] * inv;
    } else if (t < 512) {
        int c = t - 256;
        float inv = g2[c] * rsqrtf(v2[c] + EPS_BN);
        bias2[c] = b2[c] - m2[c] * inv;
    } else if (t < 1536) {
        int c = t - 512;
        float inv = g3[c] * rsqrtf(v3[c] + EPS_BN);
        bias3[c] = b3[c] - m3[c] * inv;
    }
}

__global__ void repack_w1(const float* __restrict__ w1, const float* __restrict__ g1,
                          const float* __restrict__ v1, unsigned short* __restrict__ w1b) {
    int idx = blockIdx.x * 256 + threadIdx.x;  // < 262144
    int co = idx >> 10;
    float inv = g1[co] * rsqrtf(v1[co] + EPS_BN);
    w1b[idx] = f2b(w1[idx] * inv);
}

__global__ void repack_w2(const float* __restrict__ w2, const float* __restrict__ g2,
                          const float* __restrict__ v2, unsigned short* __restrict__ w2r) {
    int idx = blockIdx.x * 256 + threadIdx.x;  // < 589824
    int k9 = idx >> 16;
    int rem = idx & 65535;
    int co = rem >> 8;
    int ci = rem & 255;
    float inv = g2[co] * rsqrtf(v2[co] + EPS_BN);
    w2r[idx] = f2b(w2[(co * 256 + ci) * 9 + k9] * inv);
}

__global__ void repack_w3(const float* __restrict__ w3, const float* __restrict__ g3,
                          const float* __restrict__ v3, unsigned short* __restrict__ w3b) {
    int idx = blockIdx.x * 256 + threadIdx.x;  // < 262144
    int co = idx >> 8;
    float inv = g3[co] * rsqrtf(v3[co] + EPS_BN);
    w3b[idx] = f2b(w3[idx] * inv);
}

// zero only the halo cells of in2p (116 cells/image * 256 ch)
__global__ void halo_zero(unsigned short* __restrict__ in2p) {
    int idx = blockIdx.x * 256 + threadIdx.x;  // 928*256 = 64*116*32
    int cell = idx >> 5, l8 = idx & 31;
    int n = cell / 116, c = cell % 116;
    int h, w;
    if (c < 30)      { h = 0;      w = c; }
    else if (c < 60) { h = 29;     w = c - 30; }
    else if (c < 88) { h = c - 59; w = 0; }
    else             { h = c - 87; w = 29; }
    uint4 z = {0u, 0u, 0u, 0u};
    *reinterpret_cast<uint4*>(in2p + (((size_t)n * 900) + h * 30 + w) * 256 + l8 * 8) = z;
}

// ---------------- transpose: x (N,1024,784) fp32 -> xt (N,784,1024) bf16 ----------------
__global__ __launch_bounds__(256) void transpose_x(const float* __restrict__ x,
                                                   unsigned short* __restrict__ xt) {
    __shared__ float t[64][65];
    const int tid = threadIdx.x;
    const int sp0 = blockIdx.x * 64;
    const int c0 = blockIdx.y * 64;
    const int n = blockIdx.z;
    const float* xn = x + (size_t)n * 1024 * 784;

#pragma unroll
    for (int it = 0; it < 4; ++it) {
        int ci = it * 16 + (tid >> 4);
        int spl = (tid & 15) * 4;
        int sp = sp0 + spl;
        float4 v = {0.f, 0.f, 0.f, 0.f};
        if (sp < 784) v = *reinterpret_cast<const float4*>(xn + (size_t)(c0 + ci) * 784 + sp);
        t[ci][spl + 0] = v.x;
        t[ci][spl + 1] = v.y;
        t[ci][spl + 2] = v.z;
        t[ci][spl + 3] = v.w;
    }
    __syncthreads();

    unsigned short* xtn = xt + (size_t)n * 784 * 1024;
#pragma unroll
    for (int it = 0; it < 2; ++it) {
        int spl = it * 32 + (tid >> 3);
        int sp = sp0 + spl;
        if (sp >= 784) continue;
        int ci8 = (tid & 7) * 8;
        float v0 = t[ci8 + 0][spl], v1 = t[ci8 + 1][spl];
        float v2 = t[ci8 + 2][spl], v3 = t[ci8 + 3][spl];
        float v4 = t[ci8 + 4][spl], v5 = t[ci8 + 5][spl];
        float v6 = t[ci8 + 6][spl], v7 = t[ci8 + 7][spl];
        uint4 o = {pack2(v0, v1), pack2(v2, v3), pack2(v4, v5), pack2(v6, v7)};
        *reinterpret_cast<uint4*>(xtn + (size_t)sp * 1024 + c0 + ci8) = o;
    }
}

// ---------------- MFMA inner step ----------------
// As[m][k] stride LDK (m = A-tile row), Bs[n][k] stride LDK (n = B-tile row).
// D: row(quad*4+reg) follows A, col(lane&15) follows B.
__device__ __forceinline__ void mfma_step(const unsigned short* As, const unsigned short* Bs,
                                          int aoff, int boff, f32x4 acc[4][4]) {
    bf16x8 a[4], b[4];
#pragma unroll
    for (int i = 0; i < 4; ++i)
        a[i] = *reinterpret_cast<const bf16x8*>(As + aoff + i * 16 * LDK);
#pragma unroll
    for (int j = 0; j < 4; ++j)
        b[j] = *reinterpret_cast<const bf16x8*>(Bs + boff + j * 16 * LDK);
#pragma unroll
    for (int i = 0; i < 4; ++i)
#pragma unroll
        for (int j = 0; j < 4; ++j)
            acc[i][j] = __builtin_amdgcn_mfma_f32_16x16x32_bf16(a[i], b[j], acc[i][j], 0, 0, 0);
}

// ---------------- conv1: 1x1 1024->256 GEMM, pipelined; out NHWC bf16 + halo ----------------
// grid (392 flat-sp tiles, 2 co tiles), 256 threads
__global__ __launch_bounds__(256) void conv1_kernel(const unsigned short* __restrict__ xt,
                                                    const unsigned short* __restrict__ w1b,
                                                    const float* __restrict__ bias1,
                                                    unsigned short* __restrict__ in2p) {
    __shared__ unsigned short As[2][TILE];
    __shared__ unsigned short Bs[2][TILE];
    const int tid = threadIdx.x;
    const int f0 = blockIdx.x * 128;
    const int m0 = blockIdx.y * 128;
    const int lane = tid & 63, wave = tid >> 6;
    const int wr = wave >> 1, wc = wave & 1;
    const int l15 = lane & 15, quad = lane >> 4;
    const int tcid = tid & 3, tcl = tid >> 2;

    const unsigned short* aptr = w1b + (size_t)(m0 + tcl) * 1024 + tcid * 8;
    const unsigned short* bptr = xt + (size_t)(f0 + tcl) * 1024 + tcid * 8;

    f32x4 acc[4][4] = {};
    const int aoff = (wr * 64 + l15) * LDK + quad * 8;
    const int boff = (wc * 64 + l15) * LDK + quad * 8;
    const int wo = tcl * LDK + tcid * 8;

    uint4 ra0, ra1, rb0, rb1;
    ra0 = *reinterpret_cast<const uint4*>(aptr);
    ra1 = *reinterpret_cast<const uint4*>(aptr + 65536);
    rb0 = *reinterpret_cast<const uint4*>(bptr);
    rb1 = *reinterpret_cast<const uint4*>(bptr + 65536);

    for (int kk = 0; kk < 32; ++kk) {
        unsigned short* A = As[kk & 1];
        unsigned short* B = Bs[kk & 1];
        *reinterpret_cast<uint4*>(A + wo) = ra0;
        *reinterpret_cast<uint4*>(A + 64 * LDK + wo) = ra1;
        *reinterpret_cast<uint4*>(B + wo) = rb0;
        *reinterpret_cast<uint4*>(B + 64 * LDK + wo) = rb1;
        if (kk < 31) {
            int k0 = (kk + 1) * 32;
            ra0 = *reinterpret_cast<const uint4*>(aptr + k0);
            ra1 = *reinterpret_cast<const uint4*>(aptr + 65536 + k0);
            rb0 = *reinterpret_cast<const uint4*>(bptr + k0);
            rb1 = *reinterpret_cast<const uint4*>(bptr + 65536 + k0);
        }
        lgkm_barrier();
        mfma_step(A, B, aoff, boff, acc);
    }

    // epilogue: bias + relu -> bf16 NHWC with +1 halo offset
#pragma unroll
    for (int j = 0; j < 4; ++j) {
        int f = f0 + wc * 64 + j * 16 + l15;
        int n = f / 784;
        int r = f - n * 784;
        int oh = r / 28, ow = r - oh * 28;
        unsigned short* dst = in2p + ((size_t)n * 900 + (oh + 1) * 30 + (ow + 1)) * 256;
#pragma unroll
        for (int i = 0; i < 4; ++i) {
            int co = m0 + wr * 64 + i * 16 + quad * 4;
            float4 bia = *reinterpret_cast<const float4*>(bias1 + co);
            f32x4 v = acc[i][j];
            ushort4 o;
            o.x = f2b(fmaxf(v.x + bia.x, 0.f));
            o.y = f2b(fmaxf(v.y + bia.y, 0.f));
            o.z = f2b(fmaxf(v.z + bia.z, 0.f));
            o.w = f2b(fmaxf(v.w + bia.w, 0.f));
            *reinterpret_cast<ushort4*>(dst + co) = o;
        }
    }
}

// ---------------- conv2: 3x3 = 72 pipelined K-steps; out flat [f][256] bf16 ----------------
// grid (392, 2), 256 threads
__global__ __launch_bounds__(256) void conv2_kernel(const unsigned short* __restrict__ in2p,
                                                    const unsigned short* __restrict__ w2r,
                                                    const float* __restrict__ bias2,
                                                    unsigned short* __restrict__ in3) {
    __shared__ unsigned short As[2][TILE];
    __shared__ unsigned short Bs[2][TILE];
    const int tid = threadIdx.x;
    const int f0 = blockIdx.x * 128;
    const int m0 = blockIdx.y * 128;
    const int lane = tid & 63, wave = tid >> 6;
    const int wr = wave >> 1, wc = wave & 1;
    const int l15 = lane & 15, quad = lane >> 4;
    const int tcid = tid & 3, tcl = tid >> 2;

    // per-thread halo-center cell index for its two B rows
    int cellc[2];
#pragma unroll
    for (int p = 0; p < 2; ++p) {
        int f = f0 + p * 64 + tcl;
        int n = f / 784;
        int r = f - n * 784;
        int oh = r / 28, ow = r - oh * 28;
        cellc[p] = n * 900 + (oh + 1) * 30 + (ow + 1);
    }

    f32x4 acc[4][4] = {};
    const int aoff = (wr * 64 + l15) * LDK + quad * 8;
    const int boff = (wc * 64 + l15) * LDK + quad * 8;
    const int wo = tcl * LDK + tcid * 8;

    uint4 ra0, ra1, rb0, rb1;
    {
        const unsigned short* wb = w2r;  // k9=0, cb=0
        ra0 = *reinterpret_cast<const uint4*>(wb + (size_t)(m0 + tcl) * 256 + tcid * 8);
        ra1 = *reinterpret_cast<const uint4*>(wb + (size_t)(m0 + 64 + tcl) * 256 + tcid * 8);
        int dd = -31;  // (0-1)*30 + (0-1)
        rb0 = *reinterpret_cast<const uint4*>(in2p + (size_t)(cellc[0] + dd) * 256 + tcid * 8);
        rb1 = *reinterpret_cast<const uint4*>(in2p + (size_t)(cellc[1] + dd) * 256 + tcid * 8);
    }

    for (int kk = 0; kk < 72; ++kk) {
        unsigned short* A = As[kk & 1];
        unsigned short* B = Bs[kk & 1];
        *reinterpret_cast<uint4*>(A + wo) = ra0;
        *reinterpret_cast<uint4*>(A + 64 * LDK + wo) = ra1;
        *reinterpret_cast<uint4*>(B + wo) = rb0;
        *reinterpret_cast<uint4*>(B + 64 * LDK + wo) = rb1;
        if (kk < 71) {
            int kn = kk + 1;
            int k9 = kn >> 3, cb = kn & 7;
            int kh = k9 / 3, kw = k9 - 3 * kh;
            int dd = (kh - 1) * 30 + (kw - 1);
            const unsigned short* wb = w2r + (size_t)k9 * 65536 + cb * 32;
            ra0 = *reinterpret_cast<const uint4*>(wb + (size_t)(m0 + tcl) * 256 + tcid * 8);
            ra1 = *reinterpret_cast<const uint4*>(wb + (size_t)(m0 + 64 + tcl) * 256 + tcid * 8);
            const unsigned short* bb = in2p + (size_t)cb * 32 + tcid * 8;
            rb0 = *reinterpret_cast<const uint4*>(bb + (size_t)(cellc[0] + dd) * 256);
            rb1 = *reinterpret_cast<const uint4*>(bb + (size_t)(cellc[1] + dd) * 256);
        }
        lgkm_barrier();
        mfma_step(A, B, aoff, boff, acc);
    }

    // epilogue: bias + relu -> bf16, flat [f][256]
#pragma unroll
    for (int j = 0; j < 4; ++j) {
        int f = f0 + wc * 64 + j * 16 + l15;
        unsigned short* dst = in3 + (size_t)f * 256;
#pragma unroll
        for (int i = 0; i < 4; ++i) {
            int co = m0 + wr * 64 + i * 16 + quad * 4;
            float4 bia = *reinterpret_cast<const float4*>(bias2 + co);
            f32x4 v = acc[i][j];
            ushort4 o;
            o.x = f2b(fmaxf(v.x + bia.x, 0.f));
            o.y = f2b(fmaxf(v.y + bia.y, 0.f));
            o.z = f2b(fmaxf(v.z + bia.z, 0.f));
            o.w = f2b(fmaxf(v.w + bia.w, 0.f));
            *reinterpret_cast<ushort4*>(dst + co) = o;
        }
    }
}

// ---------------- conv3: 1x1 256->1024, pipelined; BN + residual + ReLU, NCHW fp32 ----------------
// SWAPPED operands: A = spatial (in3 rows -> D rows = f), B = weights (w3b rows -> D cols = co).
// A lane's 4 acc regs are 4 CONSECUTIVE sp positions (4-aligned, never cross an image since
// 784 % 4 == 0) -> residual add + store become float4 ops. grid (392, 8), 256 threads
__global__ __launch_bounds__(256) void conv3_kernel(const unsigned short* __restrict__ in3,
                                                    const unsigned short* __restrict__ w3b,
                                                    const float* __restrict__ bias3,
                                                    const float* __restrict__ x,
                                                    float* __restrict__ out) {
    __shared__ unsigned short As[2][TILE];
    __shared__ unsigned short Bs[2][TILE];
    const int tid = threadIdx.x;
    const int f0 = blockIdx.x * 128;
    const int m0 = blockIdx.y * 128;
    const int lane = tid & 63, wave = tid >> 6;
    const int wr = wave >> 1, wc = wave & 1;
    const int l15 = lane & 15, quad = lane >> 4;
    const int tcid = tid & 3, tcl = tid >> 2;

    const unsigned short* aptr = in3 + (size_t)(f0 + tcl) * 256 + tcid * 8;   // spatial -> As
    const unsigned short* bptr = w3b + (size_t)(m0 + tcl) * 256 + tcid * 8;   // weights -> Bs

    f32x4 acc[4][4] = {};
    const int aoff = (wr * 64 + l15) * LDK + quad * 8;
    const int boff = (wc * 64 + l15) * LDK + quad * 8;
    const int wo = tcl * LDK + tcid * 8;

    uint4 ra0, ra1, rb0, rb1;
    ra0 = *reinterpret_cast<const uint4*>(aptr);
    ra1 = *reinterpret_cast<const uint4*>(aptr + 16384);
    rb0 = *reinterpret_cast<const uint4*>(bptr);
    rb1 = *reinterpret_cast<const uint4*>(bptr + 16384);

    for (int kk = 0; kk < 8; ++kk) {
        unsigned short* A = As[kk & 1];
        unsigned short* B = Bs[kk & 1];
        *reinterpret_cast<uint4*>(A + wo) = ra0;
        *reinterpret_cast<uint4*>(A + 64 * LDK + wo) = ra1;
        *reinterpret_cast<uint4*>(B + wo) = rb0;
        *reinterpret_cast<uint4*>(B + 64 * LDK + wo) = rb1;
        if (kk < 7) {
            int k0 = (kk + 1) * 32;
            ra0 = *reinterpret_cast<const uint4*>(aptr + k0);
            ra1 = *reinterpret_cast<const uint4*>(aptr + 16384 + k0);
            rb0 = *reinterpret_cast<const uint4*>(bptr + k0);
            rb1 = *reinterpret_cast<const uint4*>(bptr + 16384 + k0);
        }
        lgkm_barrier();
        mfma_step(A, B, aoff, boff, acc);
    }

    // epilogue: D rows = f (quad*4+reg -> 4 consecutive sp), cols = co (l15).
    // float4 residual load + float4 store per acc fragment.
#pragma unroll
    for (int j = 0; j < 4; ++j) {
        int co = m0 + wc * 64 + j * 16 + l15;
        float b = bias3[co];
#pragma unroll
        for (int i = 0; i < 4; ++i) {
            int fb = f0 + wr * 64 + i * 16 + quad * 4;
            int n = fb / 784;
            int sp = fb - n * 784;
            size_t off = ((size_t)n * 1024 + co) * 784 + sp;
            float4 xv = *reinterpret_cast<const float4*>(x + off);
            f32x4 v = acc[i][j];
            float4 o;
            o.x = fmaxf(v.x + b + xv.x, 0.f);
            o.y = fmaxf(v.y + b + xv.y, 0.f);
            o.z = fmaxf(v.z + b + xv.z, 0.f);
            o.w = fmaxf(v.w + b + xv.w, 0.f);
            *reinterpret_cast<float4*>(out + off) = o;
        }
    }
}

// ---------------- launch ----------------

extern "C" void kernel_launch(void* const* d_in, const int* in_sizes, int n_in,
                              void* d_out, int out_size, void* d_ws, size_t ws_size,
                              hipStream_t stream) {
    const float* x  = (const float*)d_in[0];
    const float* w1 = (const float*)d_in[1];
    const float* w2 = (const float*)d_in[2];
    const float* w3 = (const float*)d_in[3];
    const float* g1 = (const float*)d_in[4];
    const float* b1 = (const float*)d_in[5];
    const float* m1 = (const float*)d_in[6];
    const float* v1 = (const float*)d_in[7];
    const float* g2 = (const float*)d_in[8];
    const float* b2 = (const float*)d_in[9];
    const float* m2 = (const float*)d_in[10];
    const float* v2 = (const float*)d_in[11];
    const float* g3 = (const float*)d_in[12];
    const float* b3 = (const float*)d_in[13];
    const float* m3 = (const float*)d_in[14];
    const float* v3 = (const float*)d_in[15];

    char* ws = (char*)d_ws;
    unsigned short* w1b  = (unsigned short*)(ws + 0);         //   524288 B
    unsigned short* w2r  = (unsigned short*)(ws + 524288);    //  1179648 B
    unsigned short* w3b  = (unsigned short*)(ws + 1703936);   //   524288 B
    float* bias1         = (float*)(ws + 2228224);            //     1024 B
    float* bias2         = (float*)(ws + 2229248);            //     1024 B
    float* bias3         = (float*)(ws + 2230272);            //     4096 B
    unsigned short* in2p = (unsigned short*)(ws + 2234368);   // 29491200 B (64*900*256 bf16)
    unsigned short* xt   = (unsigned short*)(ws + 31725568);  // 102760448 B (64*784*1024 bf16)
    unsigned short* in3  = xt;  // aliases xt: xt is dead once conv1 finishes
    // total: 134486016 B (~134.5 MB)

    prep_bn_kernel<<<6, 256, 0, stream>>>(g1, b1, m1, v1, g2, b2, m2, v2, g3, b3, m3, v3,
                                          bias1, bias2, bias3);
    repack_w1<<<1024, 256, 0, stream>>>(w1, g1, v1, w1b);
    repack_w2<<<2304, 256, 0, stream>>>(w2, g2, v2, w2r);
    repack_w3<<<1024, 256, 0, stream>>>(w3, g3, v3, w3b);
    halo_zero<<<928, 256, 0, stream>>>(in2p);

    transpose_x<<<dim3(13, 16, 64), 256, 0, stream>>>(x, xt);
    conv1_kernel<<<dim3(392, 2), 256, 0, stream>>>(xt, w1b, bias1, in2p);
    conv2_kernel<<<dim3(392, 2), 256, 0, stream>>>(in2p, w2r, bias2, in3);
    conv3_kernel<<<dim3(392, 8), 256, 0, stream>>>(in3, w3b, bias3, x, (float*)d_out);
}

// Round 3
// 643.221 us; speedup vs baseline: 1.1873x; 1.0538x over previous
//
#include <hip/hip_runtime.h>
#include <hip/hip_bf16.h>
#include <cstdint>
#include <cstddef>

#define EPS_BN 1e-5f
#define LDK 40          // LDS leading-dim stride in ushorts
#define TILE (128 * LDK)

typedef __attribute__((ext_vector_type(8))) __bf16 bf16x8;
typedef __attribute__((ext_vector_type(4))) float f32x4;

__device__ __forceinline__ unsigned short f2b(float f) {
    __hip_bfloat16 h = __float2bfloat16(f);
    return __builtin_bit_cast(unsigned short, h);
}
__device__ __forceinline__ unsigned int pack2(float a, float b) {
    return (unsigned int)f2b(a) | ((unsigned int)f2b(b) << 16);
}
// wait lgkmcnt(0) only (vmcnt=63, expcnt=7 untouched), then raw barrier
__device__ __forceinline__ void lgkm_barrier() {
    __builtin_amdgcn_s_waitcnt(0xC07F);
    __builtin_amdgcn_s_barrier();
}

// ---------------- prep kernels ----------------

__global__ void prep_bn_kernel(const float* __restrict__ g1, const float* __restrict__ b1,
                               const float* __restrict__ m1, const float* __restrict__ v1,
                               const float* __restrict__ g2, const float* __restrict__ b2,
                               const float* __restrict__ m2, const float* __restrict__ v2,
                               const float* __restrict__ g3, const float* __restrict__ b3,
                               const float* __restrict__ m3, const float* __restrict__ v3,
                               float* __restrict__ bias1, float* __restrict__ bias2,
                               float* __restrict__ bias3) {
    int t = blockIdx.x * 256 + threadIdx.x;
    if (t < 256) {
        float inv = g1[t] * rsqrtf(v1[t] + EPS_BN);
        bias1[t] = b1[t] - m1[t] * inv;
    } else if (t < 512) {
        int c = t - 256;
        float inv = g2[c] * rsqrtf(v2[c] + EPS_BN);
        bias2[c] = b2[c] - m2[c] * inv;
    } else if (t < 1536) {
        int c = t - 512;
        float inv = g3[c] * rsqrtf(v3[c] + EPS_BN);
        bias3[c] = b3[c] - m3[c] * inv;
    }
}

__global__ void repack_w1(const float* __restrict__ w1, const float* __restrict__ g1,
                          const float* __restrict__ v1, unsigned short* __restrict__ w1b) {
    int idx = blockIdx.x * 256 + threadIdx.x;  // < 262144
    int co = idx >> 10;
    float inv = g1[co] * rsqrtf(v1[co] + EPS_BN);
    w1b[idx] = f2b(w1[idx] * inv);
}

__global__ void repack_w2(const float* __restrict__ w2, const float* __restrict__ g2,
                          const float* __restrict__ v2, unsigned short* __restrict__ w2r) {
    int idx = blockIdx.x * 256 + threadIdx.x;  // < 589824
    int k9 = idx >> 16;
    int rem = idx & 65535;
    int co = rem >> 8;
    int ci = rem & 255;
    float inv = g2[co] * rsqrtf(v2[co] + EPS_BN);
    w2r[idx] = f2b(w2[(co * 256 + ci) * 9 + k9] * inv);
}

__global__ void repack_w3(const float* __restrict__ w3, const float* __restrict__ g3,
                          const float* __restrict__ v3, unsigned short* __restrict__ w3b) {
    int idx = blockIdx.x * 256 + threadIdx.x;  // < 262144
    int co = idx >> 8;
    float inv = g3[co] * rsqrtf(v3[co] + EPS_BN);
    w3b[idx] = f2b(w3[idx] * inv);
}

// zero only the halo cells of in2p (116 cells/image * 256 ch)
__global__ void halo_zero(unsigned short* __restrict__ in2p) {
    int idx = blockIdx.x * 256 + threadIdx.x;  // 928*256 = 64*116*32
    int cell = idx >> 5, l8 = idx & 31;
    int n = cell / 116, c = cell % 116;
    int h, w;
    if (c < 30)      { h = 0;      w = c; }
    else if (c < 60) { h = 29;     w = c - 30; }
    else if (c < 88) { h = c - 59; w = 0; }
    else             { h = c - 87; w = 29; }
    uint4 z = {0u, 0u, 0u, 0u};
    *reinterpret_cast<uint4*>(in2p + (((size_t)n * 900) + h * 30 + w) * 256 + l8 * 8) = z;
}

// ---------------- transpose: x (N,1024,784) fp32 -> xt (N,784,1024) bf16 ----------------
__global__ __launch_bounds__(256) void transpose_x(const float* __restrict__ x,
                                                   unsigned short* __restrict__ xt) {
    __shared__ float t[64][65];
    const int tid = threadIdx.x;
    const int sp0 = blockIdx.x * 64;
    const int c0 = blockIdx.y * 64;
    const int n = blockIdx.z;
    const float* xn = x + (size_t)n * 1024 * 784;

#pragma unroll
    for (int it = 0; it < 4; ++it) {
        int ci = it * 16 + (tid >> 4);
        int spl = (tid & 15) * 4;
        int sp = sp0 + spl;
        float4 v = {0.f, 0.f, 0.f, 0.f};
        if (sp < 784) v = *reinterpret_cast<const float4*>(xn + (size_t)(c0 + ci) * 784 + sp);
        t[ci][spl + 0] = v.x;
        t[ci][spl + 1] = v.y;
        t[ci][spl + 2] = v.z;
        t[ci][spl + 3] = v.w;
    }
    __syncthreads();

    unsigned short* xtn = xt + (size_t)n * 784 * 1024;
#pragma unroll
    for (int it = 0; it < 2; ++it) {
        int spl = it * 32 + (tid >> 3);
        int sp = sp0 + spl;
        if (sp >= 784) continue;
        int ci8 = (tid & 7) * 8;
        float v0 = t[ci8 + 0][spl], v1 = t[ci8 + 1][spl];
        float v2 = t[ci8 + 2][spl], v3 = t[ci8 + 3][spl];
        float v4 = t[ci8 + 4][spl], v5 = t[ci8 + 5][spl];
        float v6 = t[ci8 + 6][spl], v7 = t[ci8 + 7][spl];
        uint4 o = {pack2(v0, v1), pack2(v2, v3), pack2(v4, v5), pack2(v6, v7)};
        *reinterpret_cast<uint4*>(xtn + (size_t)sp * 1024 + c0 + ci8) = o;
    }
}

// ---------------- MFMA inner step ----------------
// As[m][k] stride LDK (m = A-tile row), Bs[n][k] stride LDK (n = B-tile row).
// D: row(quad*4+reg) follows A, col(lane&15) follows B.
__device__ __forceinline__ void mfma_step(const unsigned short* As, const unsigned short* Bs,
                                          int aoff, int boff, f32x4 acc[4][4]) {
    bf16x8 a[4], b[4];
#pragma unroll
    for (int i = 0; i < 4; ++i)
        a[i] = *reinterpret_cast<const bf16x8*>(As + aoff + i * 16 * LDK);
#pragma unroll
    for (int j = 0; j < 4; ++j)
        b[j] = *reinterpret_cast<const bf16x8*>(Bs + boff + j * 16 * LDK);
#pragma unroll
    for (int i = 0; i < 4; ++i)
#pragma unroll
        for (int j = 0; j < 4; ++j)
            acc[i][j] = __builtin_amdgcn_mfma_f32_16x16x32_bf16(a[i], b[j], acc[i][j], 0, 0, 0);
}

// ---------------- conv1: 1x1 1024->256 GEMM, 2-deep prefetch; out NHWC bf16 + halo --------
// grid (392 flat-sp tiles, 2 co tiles), 256 threads
__global__ __launch_bounds__(256) void conv1_kernel(const unsigned short* __restrict__ xt,
                                                    const unsigned short* __restrict__ w1b,
                                                    const float* __restrict__ bias1,
                                                    unsigned short* __restrict__ in2p) {
    __shared__ unsigned short As[2][TILE];
    __shared__ unsigned short Bs[2][TILE];
    const int tid = threadIdx.x;
    const int f0 = blockIdx.x * 128;
    const int m0 = blockIdx.y * 128;
    const int lane = tid & 63, wave = tid >> 6;
    const int wr = wave >> 1, wc = wave & 1;
    const int l15 = lane & 15, quad = lane >> 4;
    const int tcid = tid & 3, tcl = tid >> 2;

    const unsigned short* aptr = w1b + (size_t)(m0 + tcl) * 1024 + tcid * 8;
    const unsigned short* bptr = xt + (size_t)(f0 + tcl) * 1024 + tcid * 8;

    f32x4 acc[4][4] = {};
    const int aoff = (wr * 64 + l15) * LDK + quad * 8;
    const int boff = (wc * 64 + l15) * LDK + quad * 8;
    const int wo = tcl * LDK + tcid * 8;

    // 2-deep register prefetch: slot0 = even k-steps, slot1 = odd
    uint4 a0s0, a1s0, b0s0, b1s0, a0s1, a1s1, b0s1, b1s1;
    a0s0 = *reinterpret_cast<const uint4*>(aptr);
    a1s0 = *reinterpret_cast<const uint4*>(aptr + 65536);
    b0s0 = *reinterpret_cast<const uint4*>(bptr);
    b1s0 = *reinterpret_cast<const uint4*>(bptr + 65536);
    a0s1 = *reinterpret_cast<const uint4*>(aptr + 32);
    a1s1 = *reinterpret_cast<const uint4*>(aptr + 65536 + 32);
    b0s1 = *reinterpret_cast<const uint4*>(bptr + 32);
    b1s1 = *reinterpret_cast<const uint4*>(bptr + 65536 + 32);

    for (int kk = 0; kk < 32; kk += 2) {
        {   // even step: slot0, LDS buf 0
            unsigned short* A = As[0];
            unsigned short* B = Bs[0];
            *reinterpret_cast<uint4*>(A + wo) = a0s0;
            *reinterpret_cast<uint4*>(A + 64 * LDK + wo) = a1s0;
            *reinterpret_cast<uint4*>(B + wo) = b0s0;
            *reinterpret_cast<uint4*>(B + 64 * LDK + wo) = b1s0;
            if (kk < 30) {
                int k0 = (kk + 2) * 32;
                a0s0 = *reinterpret_cast<const uint4*>(aptr + k0);
                a1s0 = *reinterpret_cast<const uint4*>(aptr + 65536 + k0);
                b0s0 = *reinterpret_cast<const uint4*>(bptr + k0);
                b1s0 = *reinterpret_cast<const uint4*>(bptr + 65536 + k0);
            }
            lgkm_barrier();
            mfma_step(A, B, aoff, boff, acc);
        }
        {   // odd step: slot1, LDS buf 1
            unsigned short* A = As[1];
            unsigned short* B = Bs[1];
            *reinterpret_cast<uint4*>(A + wo) = a0s1;
            *reinterpret_cast<uint4*>(A + 64 * LDK + wo) = a1s1;
            *reinterpret_cast<uint4*>(B + wo) = b0s1;
            *reinterpret_cast<uint4*>(B + 64 * LDK + wo) = b1s1;
            if (kk < 30) {
                int k0 = (kk + 3) * 32;
                a0s1 = *reinterpret_cast<const uint4*>(aptr + k0);
                a1s1 = *reinterpret_cast<const uint4*>(aptr + 65536 + k0);
                b0s1 = *reinterpret_cast<const uint4*>(bptr + k0);
                b1s1 = *reinterpret_cast<const uint4*>(bptr + 65536 + k0);
            }
            lgkm_barrier();
            mfma_step(A, B, aoff, boff, acc);
        }
    }

    // epilogue: bias + relu -> bf16 NHWC with +1 halo offset
#pragma unroll
    for (int j = 0; j < 4; ++j) {
        int f = f0 + wc * 64 + j * 16 + l15;
        int n = f / 784;
        int r = f - n * 784;
        int oh = r / 28, ow = r - oh * 28;
        unsigned short* dst = in2p + ((size_t)n * 900 + (oh + 1) * 30 + (ow + 1)) * 256;
#pragma unroll
        for (int i = 0; i < 4; ++i) {
            int co = m0 + wr * 64 + i * 16 + quad * 4;
            float4 bia = *reinterpret_cast<const float4*>(bias1 + co);
            f32x4 v = acc[i][j];
            ushort4 o;
            o.x = f2b(fmaxf(v.x + bia.x, 0.f));
            o.y = f2b(fmaxf(v.y + bia.y, 0.f));
            o.z = f2b(fmaxf(v.z + bia.z, 0.f));
            o.w = f2b(fmaxf(v.w + bia.w, 0.f));
            *reinterpret_cast<ushort4*>(dst + co) = o;
        }
    }
}

// ---------------- conv2: 3x3 = 72 k-steps, 2-deep prefetch; out flat [f][256] bf16 --------
// grid (392, 2), 256 threads
__global__ __launch_bounds__(256) void conv2_kernel(const unsigned short* __restrict__ in2p,
                                                    const unsigned short* __restrict__ w2r,
                                                    const float* __restrict__ bias2,
                                                    unsigned short* __restrict__ in3) {
    __shared__ unsigned short As[2][TILE];
    __shared__ unsigned short Bs[2][TILE];
    const int tid = threadIdx.x;
    const int f0 = blockIdx.x * 128;
    const int m0 = blockIdx.y * 128;
    const int lane = tid & 63, wave = tid >> 6;
    const int wr = wave >> 1, wc = wave & 1;
    const int l15 = lane & 15, quad = lane >> 4;
    const int tcid = tid & 3, tcl = tid >> 2;

    // per-thread halo-center cell index for its two B rows
    int cellc[2];
#pragma unroll
    for (int p = 0; p < 2; ++p) {
        int f = f0 + p * 64 + tcl;
        int n = f / 784;
        int r = f - n * 784;
        int oh = r / 28, ow = r - oh * 28;
        cellc[p] = n * 900 + (oh + 1) * 30 + (ow + 1);
    }

    f32x4 acc[4][4] = {};
    const int aoff = (wr * 64 + l15) * LDK + quad * 8;
    const int boff = (wc * 64 + l15) * LDK + quad * 8;
    const int wo = tcl * LDK + tcid * 8;

    uint4 a0s0, a1s0, b0s0, b1s0, a0s1, a1s1, b0s1, b1s1;
    {   // kn=0: k9=0, cb=0, dd=-31
        a0s0 = *reinterpret_cast<const uint4*>(w2r + (size_t)(m0 + tcl) * 256 + tcid * 8);
        a1s0 = *reinterpret_cast<const uint4*>(w2r + (size_t)(m0 + 64 + tcl) * 256 + tcid * 8);
        b0s0 = *reinterpret_cast<const uint4*>(in2p + (size_t)(cellc[0] - 31) * 256 + tcid * 8);
        b1s0 = *reinterpret_cast<const uint4*>(in2p + (size_t)(cellc[1] - 31) * 256 + tcid * 8);
    }
    {   // kn=1: k9=0, cb=1, dd=-31
        const unsigned short* wb = w2r + 32;
        a0s1 = *reinterpret_cast<const uint4*>(wb + (size_t)(m0 + tcl) * 256 + tcid * 8);
        a1s1 = *reinterpret_cast<const uint4*>(wb + (size_t)(m0 + 64 + tcl) * 256 + tcid * 8);
        const unsigned short* bb = in2p + 32 + tcid * 8;
        b0s1 = *reinterpret_cast<const uint4*>(bb + (size_t)(cellc[0] - 31) * 256);
        b1s1 = *reinterpret_cast<const uint4*>(bb + (size_t)(cellc[1] - 31) * 256);
    }

    for (int kk = 0; kk < 72; kk += 2) {
        {   // even step: slot0, LDS buf 0
            unsigned short* A = As[0];
            unsigned short* B = Bs[0];
            *reinterpret_cast<uint4*>(A + wo) = a0s0;
            *reinterpret_cast<uint4*>(A + 64 * LDK + wo) = a1s0;
            *reinterpret_cast<uint4*>(B + wo) = b0s0;
            *reinterpret_cast<uint4*>(B + 64 * LDK + wo) = b1s0;
            if (kk < 70) {
                int kn = kk + 2;
                int k9 = kn >> 3, cb = kn & 7;
                int kh = k9 / 3, kw = k9 - 3 * kh;
                int dd = (kh - 1) * 30 + (kw - 1);
                const unsigned short* wb = w2r + (size_t)k9 * 65536 + cb * 32;
                a0s0 = *reinterpret_cast<const uint4*>(wb + (size_t)(m0 + tcl) * 256 + tcid * 8);
                a1s0 = *reinterpret_cast<const uint4*>(wb + (size_t)(m0 + 64 + tcl) * 256 + tcid * 8);
                const unsigned short* bb = in2p + (size_t)cb * 32 + tcid * 8;
                b0s0 = *reinterpret_cast<const uint4*>(bb + (size_t)(cellc[0] + dd) * 256);
                b1s0 = *reinterpret_cast<const uint4*>(bb + (size_t)(cellc[1] + dd) * 256);
            }
            lgkm_barrier();
            mfma_step(A, B, aoff, boff, acc);
        }
        {   // odd step: slot1, LDS buf 1
            unsigned short* A = As[1];
            unsigned short* B = Bs[1];
            *reinterpret_cast<uint4*>(A + wo) = a0s1;
            *reinterpret_cast<uint4*>(A + 64 * LDK + wo) = a1s1;
            *reinterpret_cast<uint4*>(B + wo) = b0s1;
            *reinterpret_cast<uint4*>(B + 64 * LDK + wo) = b1s1;
            if (kk < 70) {
                int kn = kk + 3;
                int k9 = kn >> 3, cb = kn & 7;
                int kh = k9 / 3, kw = k9 - 3 * kh;
                int dd = (kh - 1) * 30 + (kw - 1);
                const unsigned short* wb = w2r + (size_t)k9 * 65536 + cb * 32;
                a0s1 = *reinterpret_cast<const uint4*>(wb + (size_t)(m0 + tcl) * 256 + tcid * 8);
                a1s1 = *reinterpret_cast<const uint4*>(wb + (size_t)(m0 + 64 + tcl) * 256 + tcid * 8);
                const unsigned short* bb = in2p + (size_t)cb * 32 + tcid * 8;
                b0s1 = *reinterpret_cast<const uint4*>(bb + (size_t)(cellc[0] + dd) * 256);
                b1s1 = *reinterpret_cast<const uint4*>(bb + (size_t)(cellc[1] + dd) * 256);
            }
            lgkm_barrier();
            mfma_step(A, B, aoff, boff, acc);
        }
    }

    // epilogue: bias + relu -> bf16, flat [f][256]
#pragma unroll
    for (int j = 0; j < 4; ++j) {
        int f = f0 + wc * 64 + j * 16 + l15;
        unsigned short* dst = in3 + (size_t)f * 256;
#pragma unroll
        for (int i = 0; i < 4; ++i) {
            int co = m0 + wr * 64 + i * 16 + quad * 4;
            float4 bia = *reinterpret_cast<const float4*>(bias2 + co);
            f32x4 v = acc[i][j];
            ushort4 o;
            o.x = f2b(fmaxf(v.x + bia.x, 0.f));
            o.y = f2b(fmaxf(v.y + bia.y, 0.f));
            o.z = f2b(fmaxf(v.z + bia.z, 0.f));
            o.w = f2b(fmaxf(v.w + bia.w, 0.f));
            *reinterpret_cast<ushort4*>(dst + co) = o;
        }
    }
}

// ---------------- conv3: 1x1 256->1024; x-prefetch + 2-deep staging; BN+res+ReLU fp32 -----
// A = spatial (in3 rows -> D rows = f), B = weights (w3b rows -> D cols = co).
// Residual x is prefetched into registers BEFORE the k-loop so its HBM traffic overlaps
// the staging/MFMA phase. grid (392, 8), 256 threads
__global__ __launch_bounds__(256) void conv3_kernel(const unsigned short* __restrict__ in3,
                                                    const unsigned short* __restrict__ w3b,
                                                    const float* __restrict__ bias3,
                                                    const float* __restrict__ x,
                                                    float* __restrict__ out) {
    __shared__ unsigned short As[2][TILE];
    __shared__ unsigned short Bs[2][TILE];
    const int tid = threadIdx.x;
    const int f0 = blockIdx.x * 128;
    const int m0 = blockIdx.y * 128;
    const int lane = tid & 63, wave = tid >> 6;
    const int wr = wave >> 1, wc = wave & 1;
    const int l15 = lane & 15, quad = lane >> 4;
    const int tcid = tid & 3, tcl = tid >> 2;

    const unsigned short* aptr = in3 + (size_t)(f0 + tcl) * 256 + tcid * 8;   // spatial -> As
    const unsigned short* bptr = w3b + (size_t)(m0 + tcl) * 256 + tcid * 8;   // weights -> Bs

    f32x4 acc[4][4] = {};
    const int aoff = (wr * 64 + l15) * LDK + quad * 8;
    const int boff = (wc * 64 + l15) * LDK + quad * 8;
    const int wo = tcl * LDK + tcid * 8;

    // staging prologue first (so the first ds_writes only wait on these, not on x)
    uint4 a0s0, a1s0, b0s0, b1s0, a0s1, a1s1, b0s1, b1s1;
    a0s0 = *reinterpret_cast<const uint4*>(aptr);
    a1s0 = *reinterpret_cast<const uint4*>(aptr + 16384);
    b0s0 = *reinterpret_cast<const uint4*>(bptr);
    b1s0 = *reinterpret_cast<const uint4*>(bptr + 16384);
    a0s1 = *reinterpret_cast<const uint4*>(aptr + 32);
    a1s1 = *reinterpret_cast<const uint4*>(aptr + 16384 + 32);
    b0s1 = *reinterpret_cast<const uint4*>(bptr + 32);
    b1s1 = *reinterpret_cast<const uint4*>(bptr + 16384 + 32);

    // residual prefetch: 16 float4, consumed only in the epilogue
    float4 xv[16];
#pragma unroll
    for (int j = 0; j < 4; ++j) {
        int co = m0 + wc * 64 + j * 16 + l15;
#pragma unroll
        for (int i = 0; i < 4; ++i) {
            int fb = f0 + wr * 64 + i * 16 + quad * 4;
            int n = fb / 784;
            int sp = fb - n * 784;
            xv[j * 4 + i] = *reinterpret_cast<const float4*>(x + ((size_t)n * 1024 + co) * 784 + sp);
        }
    }

    for (int kk = 0; kk < 8; kk += 2) {
        {   // even step: slot0, LDS buf 0
            unsigned short* A = As[0];
            unsigned short* B = Bs[0];
            *reinterpret_cast<uint4*>(A + wo) = a0s0;
            *reinterpret_cast<uint4*>(A + 64 * LDK + wo) = a1s0;
            *reinterpret_cast<uint4*>(B + wo) = b0s0;
            *reinterpret_cast<uint4*>(B + 64 * LDK + wo) = b1s0;
            if (kk < 6) {
                int k0 = (kk + 2) * 32;
                a0s0 = *reinterpret_cast<const uint4*>(aptr + k0);
                a1s0 = *reinterpret_cast<const uint4*>(aptr + 16384 + k0);
                b0s0 = *reinterpret_cast<const uint4*>(bptr + k0);
                b1s0 = *reinterpret_cast<const uint4*>(bptr + 16384 + k0);
            }
            lgkm_barrier();
            mfma_step(A, B, aoff, boff, acc);
        }
        {   // odd step: slot1, LDS buf 1
            unsigned short* A = As[1];
            unsigned short* B = Bs[1];
            *reinterpret_cast<uint4*>(A + wo) = a0s1;
            *reinterpret_cast<uint4*>(A + 64 * LDK + wo) = a1s1;
            *reinterpret_cast<uint4*>(B + wo) = b0s1;
            *reinterpret_cast<uint4*>(B + 64 * LDK + wo) = b1s1;
            if (kk < 6) {
                int k0 = (kk + 3) * 32;
                a0s1 = *reinterpret_cast<const uint4*>(aptr + k0);
                a1s1 = *reinterpret_cast<const uint4*>(aptr + 16384 + k0);
                b0s1 = *reinterpret_cast<const uint4*>(bptr + k0);
                b1s1 = *reinterpret_cast<const uint4*>(bptr + 16384 + k0);
            }
            lgkm_barrier();
            mfma_step(A, B, aoff, boff, acc);
        }
    }

    // epilogue: D rows = f (quad*4+reg -> 4 consecutive sp), cols = co (l15).
#pragma unroll
    for (int j = 0; j < 4; ++j) {
        int co = m0 + wc * 64 + j * 16 + l15;
        float b = bias3[co];
#pragma unroll
        for (int i = 0; i < 4; ++i) {
            int fb = f0 + wr * 64 + i * 16 + quad * 4;
            int n = fb / 784;
            int sp = fb - n * 784;
            size_t off = ((size_t)n * 1024 + co) * 784 + sp;
            float4 xr = xv[j * 4 + i];
            f32x4 v = acc[i][j];
            float4 o;
            o.x = fmaxf(v.x + b + xr.x, 0.f);
            o.y = fmaxf(v.y + b + xr.y, 0.f);
            o.z = fmaxf(v.z + b + xr.z, 0.f);
            o.w = fmaxf(v.w + b + xr.w, 0.f);
            *reinterpret_cast<float4*>(out + off) = o;
        }
    }
}

// ---------------- launch ----------------

extern "C" void kernel_launch(void* const* d_in, const int* in_sizes, int n_in,
                              void* d_out, int out_size, void* d_ws, size_t ws_size,
                              hipStream_t stream) {
    const float* x  = (const float*)d_in[0];
    const float* w1 = (const float*)d_in[1];
    const float* w2 = (const float*)d_in[2];
    const float* w3 = (const float*)d_in[3];
    const float* g1 = (const float*)d_in[4];
    const float* b1 = (const float*)d_in[5];
    const float* m1 = (const float*)d_in[6];
    const float* v1 = (const float*)d_in[7];
    const float* g2 = (const float*)d_in[8];
    const float* b2 = (const float*)d_in[9];
    const float* m2 = (const float*)d_in[10];
    const float* v2 = (const float*)d_in[11];
    const float* g3 = (const float*)d_in[12];
    const float* b3 = (const float*)d_in[13];
    const float* m3 = (const float*)d_in[14];
    const float* v3 = (const float*)d_in[15];

    char* ws = (char*)d_ws;
    unsigned short* w1b  = (unsigned short*)(ws + 0);         //   524288 B
    unsigned short* w2r  = (unsigned short*)(ws + 524288);    //  1179648 B
    unsigned short* w3b  = (unsigned short*)(ws + 1703936);   //   524288 B
    float* bias1         = (float*)(ws + 2228224);            //     1024 B
    float* bias2         = (float*)(ws + 2229248);            //     1024 B
    float* bias3         = (float*)(ws + 2230272);            //     4096 B
    unsigned short* in2p = (unsigned short*)(ws + 2234368);   // 29491200 B (64*900*256 bf16)
    unsigned short* xt   = (unsigned short*)(ws + 31725568);  // 102760448 B (64*784*1024 bf16)
    unsigned short* in3  = xt;  // aliases xt: xt is dead once conv1 finishes
    // total: 134486016 B (~134.5 MB)

    prep_bn_kernel<<<6, 256, 0, stream>>>(g1, b1, m1, v1, g2, b2, m2, v2, g3, b3, m3, v3,
                                          bias1, bias2, bias3);
    repack_w1<<<1024, 256, 0, stream>>>(w1, g1, v1, w1b);
    repack_w2<<<2304, 256, 0, stream>>>(w2, g2, v2, w2r);
    repack_w3<<<1024, 256, 0, stream>>>(w3, g3, v3, w3b);
    halo_zero<<<928, 256, 0, stream>>>(in2p);

    transpose_x<<<dim3(13, 16, 64), 256, 0, stream>>>(x, xt);
    conv1_kernel<<<dim3(392, 2), 256, 0, stream>>>(xt, w1b, bias1, in2p);
    conv2_kernel<<<dim3(392, 2), 256, 0, stream>>>(in2p, w2r, bias2, in3);
    conv3_kernel<<<dim3(392, 8), 256, 0, stream>>>(in3, w3b, bias3, x, (float*)d_out);
}